// Round 8
// baseline (380.140 us; speedup 1.0000x reference)
//
#include <hip/hip_runtime.h>
#include <hip/hip_bf16.h>
#include <hip/hip_fp16.h>

#define OUT_F 4096
#define IN_F  4096
#define BATCH 4096
#define RANK  32
#define KPAD  4160   // 4096 + 32 (svd ext) + 32 (zero pad) = 65 * 64
#define NT    65     // K tiles of 64

typedef __hip_bfloat16 bf16;
using bf16x8 = __attribute__((ext_vector_type(8))) short;
using f32x4  = __attribute__((ext_vector_type(4))) float;

__device__ __forceinline__ void gload_lds16(const void* g, void* l) {
  __builtin_amdgcn_global_load_lds(
      (const __attribute__((address_space(1))) unsigned int*)g,
      (__attribute__((address_space(3))) unsigned int*)l,
      16, 0, 0);
}

__device__ __forceinline__ unsigned short bf16_bits(float f) {
  bf16 h = __float2bfloat16(f);
  return *(unsigned short*)&h;
}

#define SBAR() asm volatile("s_barrier" ::: "memory")

// ---------------------------------------------------------------------------
// A-prep: xs[b,c] = x[b,c] * scales[c/128]  (bf16), zero the pad cols.
__global__ __launch_bounds__(256) void prep_xs(const float* __restrict__ x,
                                               const float* __restrict__ scales,
                                               bf16* __restrict__ A) {
  int b = blockIdx.x;
  int tid = threadIdx.x;
  const float4* xr = (const float4*)(x + (size_t)b * IN_F);
  bf16* Ar = A + (size_t)b * KPAD;
#pragma unroll
  for (int j = 0; j < 4; ++j) {
    int f = tid + j * 256;               // float4 index in [0,1024)
    float4 xv = xr[f];
    float sv = scales[f >> 5];
    ushort4 pk = make_ushort4(bf16_bits(xv.x * sv), bf16_bits(xv.y * sv),
                              bf16_bits(xv.z * sv), bf16_bits(xv.w * sv));
    *(ushort4*)(Ar + 4 * (size_t)f) = pk;
  }
  if (tid < 32) {
    bf16 z = __float2bfloat16(0.0f);
    Ar[IN_F + RANK + tid] = z;
  }
}

// ---------------------------------------------------------------------------
// Small prep: [0,512) VsT[r][c] = V[c][r]/s[c/128]; [512,1536) B ext cols
// (U values, 0 pad). Protected rows handled separately AFTER prep_b.
__global__ __launch_bounds__(256) void prep_misc(const float* __restrict__ v,
                                                 const float* __restrict__ scales,
                                                 const float* __restrict__ u,
                                                 bf16* __restrict__ vst,
                                                 bf16* __restrict__ B) {
  int bid = blockIdx.x;
  if (bid < 512) {
    int gid = bid * 256 + threadIdx.x;       // [0, 131072)
    int c = gid >> 5, r = gid & 31;
    float val = v[(size_t)c * RANK + r] / scales[c >> 7];
    vst[(size_t)r * IN_F + c] = __float2bfloat16(val);
  } else {
    int i = (bid - 512) * 256 + threadIdx.x; // [0, 262144)
    int o = i >> 6, j = i & 63;
    float val = (j < RANK) ? u[o * RANK + j] : 0.f;
    B[(size_t)o * KPAD + IN_F + j] = __float2bfloat16(val);
  }
}

// ---------------------------------------------------------------------------
// T = xs @ VsT^T via MFMA into A cols 4096..4127 (x@V == (x·s)@(V/s)).
__global__ __launch_bounds__(64) void prep_t_mfma(const bf16* __restrict__ A_ro,
                                                  const bf16* __restrict__ vst,
                                                  bf16* __restrict__ A_wr) {
  int lane = threadIdx.x;
  int row0 = blockIdx.x * 16;
  const bf16* arow  = A_ro + (size_t)(row0 + (lane & 15)) * KPAD + ((lane >> 4) << 3);
  const bf16* brow0 = vst + (size_t)(lane & 15) * IN_F + ((lane >> 4) << 3);
  const bf16* brow1 = vst + (size_t)(16 + (lane & 15)) * IN_F + ((lane >> 4) << 3);
  f32x4 acc0 = (f32x4){0.f, 0.f, 0.f, 0.f};
  f32x4 acc1 = (f32x4){0.f, 0.f, 0.f, 0.f};
#pragma unroll 8
  for (int k0 = 0; k0 < IN_F; k0 += 32) {
    bf16x8 av  = *(const bf16x8*)(arow + k0);
    bf16x8 bv0 = *(const bf16x8*)(brow0 + k0);
    bf16x8 bv1 = *(const bf16x8*)(brow1 + k0);
    acc0 = __builtin_amdgcn_mfma_f32_16x16x32_bf16(av, bv0, acc0, 0, 0, 0);
    acc1 = __builtin_amdgcn_mfma_f32_16x16x32_bf16(av, bv1, acc1, 0, 0, 0);
  }
#pragma unroll
  for (int r = 0; r < 4; ++r) {
    int row = row0 + ((lane >> 4) << 2) + r;
    bf16* Tr = A_wr + (size_t)row * KPAD + IN_F;
    Tr[lane & 15]        = __float2bfloat16(acc0[r]);
    Tr[16 + (lane & 15)] = __float2bfloat16(acc1[r]);
  }
}

// ---------------------------------------------------------------------------
// B-unpack: split-layout nibbles. lo nibbles -> rows 0..2047, hi -> 2048..4095.
__global__ __launch_bounds__(256) void prep_b(const int* __restrict__ packed,
                                              bf16* __restrict__ B) {
  size_t i = (size_t)blockIdx.x * 256 + threadIdx.x;   // [0, 2097152)
  int4 p = ((const int4*)packed)[i];
  size_t e = i * 4;
  int o = (int)(e >> 12);
  int c = (int)(e & 4095);
  int vals[4] = {p.x, p.y, p.z, p.w};
  unsigned short lo[4], hi[4];
#pragma unroll
  for (int j = 0; j < 4; ++j) {
    lo[j] = bf16_bits((float)((vals[j] & 15) - 8));
    hi[j] = bf16_bits((float)(((vals[j] >> 4) & 15) - 8));
  }
  *(ushort4*)(B + (size_t)o * KPAD + c) = make_ushort4(lo[0], lo[1], lo[2], lo[3]);
  *(ushort4*)(B + (size_t)(o + 2048) * KPAD + c) = make_ushort4(hi[0], hi[1], hi[2], hi[3]);
}

// ---------------------------------------------------------------------------
// Protected rows — MUST run after prep_b (overwrites unpacked rows) and after
// prep_misc (overwrites ext cols with 0). A carries x*s, so rows carry pc/s.
__global__ __launch_bounds__(256) void prep_prot(const float* __restrict__ pc,
                                                 const float* __restrict__ scales,
                                                 const int* __restrict__ pidx,
                                                 bf16* __restrict__ B) {
  int bi = blockIdx.x;            // [0, 32)
  int row = pidx[bi];
  bf16* Br = B + (size_t)row * KPAD;
  for (int c = threadIdx.x; c < KPAD; c += 256) {
    float val = (c < IN_F) ? pc[(size_t)bi * IN_F + c] / scales[c >> 7] : 0.f;
    Br[c] = __float2bfloat16(val);
  }
}

// ---------------------------------------------------------------------------
// Main GEMM, 256x256 tile, BK=64, 8 waves (4 row-bands x 2 col-bands).
// A: direct global->VGPR (L2-resident panels), double-set prefetch.
// B: 4-deep LDS pipeline, counted vmcnt(4) at tile boundaries (never 0).
// 4 phases/tile: {ds_read 4xb128, 1 B-stage round, s_barrier, setprio(1),
//                 16 MFMA, setprio(0), s_barrier}.
__global__ __launch_bounds__(512, 2) void gemm_bt(const bf16* __restrict__ A,
                                                  const bf16* __restrict__ B,
                                                  float* __restrict__ out) {
  __shared__ __align__(16) bf16 Bs[4 * 256 * 64];   // 128 KiB

  int bid = blockIdx.x;
  // XCD swizzle: 256 blocks, 8 XCDs, 32 contiguous per XCD.
  int swz = (bid & 7) * 32 + (bid >> 3);
  int brow = (swz >> 4) << 8;   // batch-row tile base
  int bcol = (swz & 15) << 8;   // out-col tile base

  int tid = threadIdx.x;
  int lane = tid & 63;
  int wave = tid >> 6;
  int wr = wave >> 1;           // 0..3 : 64-row band
  int wc = wave & 1;            // 0..1 : 128-col band

  f32x4 acc[4][8];
#pragma unroll
  for (int m = 0; m < 4; ++m)
#pragma unroll
    for (int n = 0; n < 8; ++n)
      acc[m][n] = (f32x4){0.f, 0.f, 0.f, 0.f};

  // A fragment row pointers (global). Frag (m,kk): 16B at arow[m] + k0 + kk*32.
  const bf16* arow[4];
#pragma unroll
  for (int m = 0; m < 4; ++m)
    arow[m] = A + (size_t)(brow + wr * 64 + m * 16 + (lane & 15)) * KPAD +
              ((lane >> 4) << 3);

  // B LDS frag byte offsets within one 32KB buffer (kk=0; kk=1 is ^64).
  int boff[8];
#pragma unroll
  for (int n = 0; n < 8; ++n) {
    int rb = wc * 128 + n * 16 + (lane & 15);
    int s0 = (lane >> 4) ^ (rb & 7);
    boff[n] = rb * 128 + (s0 << 4);
  }

  // B staging: 4 rounds/tile; round q: idx = q*512+tid -> row=idx>>3, slot=idx&7.
  // LDS dest linear, global source slot pre-swizzled (slot ^ (row&7)).
  const bf16* gB[4]; int lB[4];
#pragma unroll
  for (int q = 0; q < 4; ++q) {
    int idx = q * 512 + tid;
    int row = idx >> 3, slot = idx & 7;
    gB[q] = B + (size_t)(bcol + row) * KPAD + ((slot ^ (row & 7)) << 3);
    lB[q] = idx << 4;          // byte offset within a buffer
  }
  char* bs0 = (char*)Bs;

  // ---- prologue: A(0) -> a0; stage B(0),B(1),B(2); newest 8 may stay in flight.
  bf16x8 a0[4][2], a1[4][2];
#pragma unroll
  for (int m = 0; m < 4; ++m)
#pragma unroll
    for (int kk = 0; kk < 2; ++kk)
      a0[m][kk] = *(const bf16x8*)(arow[m] + kk * 32);
#pragma unroll
  for (int kt = 0; kt < 3; ++kt)
#pragma unroll
    for (int q = 0; q < 4; ++q)
      gload_lds16(gB[q] + kt * 64, bs0 + kt * 32768 + lB[q]);
  asm volatile("s_waitcnt vmcnt(8)" ::: "memory");
  SBAR();

  // ---- tile body ----
  auto tile_body = [&](int t, bf16x8 (&Au)[4][2], bf16x8 (&Ap)[4][2], bool pref) {
    const char* rb = bs0 + (t & 3) * 32768;          // read buffer
    char* wb = bs0 + ((t + 3) & 3) * 32768;          // stage dest buffer
    int kt = (t + 3 < NT) ? (t + 3) : (NT - 1);      // clamped (uniform count)
    int k0n = (t + 1) * 64;
#pragma unroll
    for (int p = 0; p < 4; ++p) {
      if (p == 0 && pref) {
#pragma unroll
        for (int m = 0; m < 4; ++m)
#pragma unroll
          for (int kk = 0; kk < 2; ++kk)
            Ap[m][kk] = *(const bf16x8*)(arow[m] + k0n + kk * 32);
      }
      bf16x8 bv0k0 = *(const bf16x8*)(rb + boff[2 * p]);
      bf16x8 bv0k1 = *(const bf16x8*)(rb + (boff[2 * p] ^ 64));
      bf16x8 bv1k0 = *(const bf16x8*)(rb + boff[2 * p + 1]);
      bf16x8 bv1k1 = *(const bf16x8*)(rb + (boff[2 * p + 1] ^ 64));
      gload_lds16(gB[p] + (size_t)kt * 64, wb + lB[p]);   // 1 round/phase
      SBAR();
      __builtin_amdgcn_s_setprio(1);
#pragma unroll
      for (int m = 0; m < 4; ++m) {
        acc[m][2 * p]     = __builtin_amdgcn_mfma_f32_16x16x32_bf16(Au[m][0], bv0k0, acc[m][2 * p], 0, 0, 0);
        acc[m][2 * p]     = __builtin_amdgcn_mfma_f32_16x16x32_bf16(Au[m][1], bv0k1, acc[m][2 * p], 0, 0, 0);
        acc[m][2 * p + 1] = __builtin_amdgcn_mfma_f32_16x16x32_bf16(Au[m][0], bv1k0, acc[m][2 * p + 1], 0, 0, 0);
        acc[m][2 * p + 1] = __builtin_amdgcn_mfma_f32_16x16x32_bf16(Au[m][1], bv1k1, acc[m][2 * p + 1], 0, 0, 0);
      }
      __builtin_amdgcn_s_setprio(0);
      if (p == 3) asm volatile("s_waitcnt vmcnt(4)" ::: "memory");
      SBAR();
    }
  };

  for (int t = 0; t < NT - 1; t += 2) {
    tile_body(t, a0, a1, true);
    tile_body(t + 1, a1, a0, true);
  }
  tile_body(NT - 1, a0, a1, false);   // tail (NT odd: uses a0)

  // ---- epilogue: C/D col=lane&15 (o), row=(lane>>4)*4+r (batch); fp16 round.
#pragma unroll
  for (int m = 0; m < 4; ++m)
#pragma unroll
    for (int n = 0; n < 8; ++n)
#pragma unroll
      for (int r = 0; r < 4; ++r) {
        int mm = brow + wr * 64 + m * 16 + ((lane >> 4) << 2) + r;
        int nn = bcol + wc * 128 + n * 16 + (lane & 15);
        out[(size_t)mm * OUT_F + nn] = __half2float(__float2half(acc[m][n][r]));
      }
  asm volatile("s_waitcnt vmcnt(0)" ::: "memory");  // drain tail DMAs
}

// ---------------------------------------------------------------------------
extern "C" void kernel_launch(void* const* d_in, const int* in_sizes, int n_in,
                              void* d_out, int out_size, void* d_ws, size_t ws_size,
                              hipStream_t stream) {
  const float* x      = (const float*)d_in[0];
  const int*   packed = (const int*)d_in[1];
  const float* scales = (const float*)d_in[2];
  const float* svd_u  = (const float*)d_in[3];
  const float* svd_v  = (const float*)d_in[4];
  const float* pc     = (const float*)d_in[5];
  const int*   pidx   = (const int*)d_in[6];
  float* out = (float*)d_out;

  bf16* A   = (bf16*)d_ws;                     // [BATCH][KPAD] = 34.1 MB
  bf16* B   = A + (size_t)BATCH * KPAD;        // [OUT_F][KPAD] = 34.1 MB
  bf16* vst = B + (size_t)OUT_F * KPAD;        // [RANK][IN_F]  = 0.25 MB

  // ORDER MATTERS: prep_prot must be LAST writer of B's protected rows
  // (after prep_b's unpack and prep_misc's ext-col writes).
  prep_xs    <<<BATCH, 256, 0, stream>>>(x, scales, A);
  prep_misc  <<<1536,  256, 0, stream>>>(svd_v, scales, svd_u, vst, B);
  prep_t_mfma<<<256,   64,  0, stream>>>(A, vst, A);
  prep_b     <<<8192,  256, 0, stream>>>(packed, B);
  prep_prot  <<<32,    256, 0, stream>>>(pc, scales, pidx, B);
  gemm_bt    <<<256,   512, 0, stream>>>(A, B, out);
}

// Round 9
// 328.530 us; speedup vs baseline: 1.1571x; 1.1571x over previous
//
#include <hip/hip_runtime.h>
#include <hip/hip_bf16.h>
#include <hip/hip_fp16.h>

#define OUT_F 4096
#define IN_F  4096
#define BATCH 4096
#define RANK  32
#define KPAD  4160   // 4096 + 32 (svd ext) + 32 (zero pad) = 65 * 64 = 130 * 32
#define NKB   130    // k32-blocks per row-panel
#define NT    65     // K tiles of 64

typedef __hip_bfloat16 bf16;
using bf16x8 = __attribute__((ext_vector_type(8))) short;
using f32x4  = __attribute__((ext_vector_type(4))) float;

// Fragment-major A layout: frag(rb=row>>4, kb=k>>5) is 1024B at
// ((rb*NKB + kb) * 1024); within it byte lane*16 = lane's bf16x8, where
// lane = (k-octet<<4) | (row&15)  -> element (row, k) at
// koct*256 + (row&15)*16 + (k&7)*2.  GEMM A-load = 1 coalesced 1KB txn.

__device__ __forceinline__ void gload_lds16(const void* g, void* l) {
  __builtin_amdgcn_global_load_lds(
      (const __attribute__((address_space(1))) unsigned int*)g,
      (__attribute__((address_space(3))) unsigned int*)l,
      16, 0, 0);
}

__device__ __forceinline__ unsigned short bf16_bits(float f) {
  bf16 h = __float2bfloat16(f);
  return *(unsigned short*)&h;
}

#define SBAR() asm volatile("s_barrier" ::: "memory")

// ---------------------------------------------------------------------------
// A-prep: xs[b,c] = x[b,c]*scales[c/128], written FRAGMENT-MAJOR (see above).
// Zero for k >= IN_F (blocks 128,129); prep_t later fills block 128.
__global__ __launch_bounds__(256) void prep_xs(const float* __restrict__ x,
                                               const float* __restrict__ scales,
                                               bf16* __restrict__ A) {
  int bid  = blockIdx.x;          // 512 blocks
  int rb   = bid >> 1;            // row-block 0..255
  int half = bid & 1;
  int t = threadIdx.x;
  int lane = t & 63;
  int row = lane & 15, koct = lane >> 4;
  const float* xr = x + (size_t)(rb * 16 + row) * IN_F;
  for (int k32 = (t >> 6) + half * 4; k32 < NKB; k32 += 8) {
    int k = k32 * 32 + koct * 8;
    bf16x8 pk = (bf16x8){0, 0, 0, 0, 0, 0, 0, 0};
    if (k < IN_F) {
      float sv = scales[k >> 7];       // k..k+7 share one 128-group
      float4 v0 = *(const float4*)(xr + k);
      float4 v1 = *(const float4*)(xr + k + 4);
      pk[0] = (short)bf16_bits(v0.x * sv);
      pk[1] = (short)bf16_bits(v0.y * sv);
      pk[2] = (short)bf16_bits(v0.z * sv);
      pk[3] = (short)bf16_bits(v0.w * sv);
      pk[4] = (short)bf16_bits(v1.x * sv);
      pk[5] = (short)bf16_bits(v1.y * sv);
      pk[6] = (short)bf16_bits(v1.z * sv);
      pk[7] = (short)bf16_bits(v1.w * sv);
    }
    *(bf16x8*)(A + ((size_t)rb * NKB + k32) * 512 + (size_t)lane * 8) = pk;
  }
}

// ---------------------------------------------------------------------------
// Small prep: [0,512) VsT[r][c] = V[c][r]/s[c/128]; [512,1536) B ext cols
// (U values, 0 pad). Protected rows handled separately AFTER prep_b.
__global__ __launch_bounds__(256) void prep_misc(const float* __restrict__ v,
                                                 const float* __restrict__ scales,
                                                 const float* __restrict__ u,
                                                 bf16* __restrict__ vst,
                                                 bf16* __restrict__ B) {
  int bid = blockIdx.x;
  if (bid < 512) {
    int gid = bid * 256 + threadIdx.x;       // [0, 131072)
    int c = gid >> 5, r = gid & 31;
    float val = v[(size_t)c * RANK + r] / scales[c >> 7];
    vst[(size_t)r * IN_F + c] = __float2bfloat16(val);
  } else {
    int i = (bid - 512) * 256 + threadIdx.x; // [0, 262144)
    int o = i >> 6, j = i & 63;
    float val = (j < RANK) ? u[o * RANK + j] : 0.f;
    B[(size_t)o * KPAD + IN_F + j] = __float2bfloat16(val);
  }
}

// ---------------------------------------------------------------------------
// T = xs @ VsT^T via MFMA, reading frag-major A, writing frag-major block 128.
__global__ __launch_bounds__(64) void prep_t_mfma(const bf16* __restrict__ Af,
                                                  const bf16* __restrict__ vst,
                                                  bf16* __restrict__ Aw) {
  int lane = threadIdx.x;
  int rb = blockIdx.x;             // row-block 0..255
  const bf16* abase = Af + (size_t)rb * NKB * 512 + (size_t)lane * 8;
  const bf16* brow0 = vst + (size_t)(lane & 15) * IN_F + ((lane >> 4) << 3);
  const bf16* brow1 = vst + (size_t)(16 + (lane & 15)) * IN_F + ((lane >> 4) << 3);
  f32x4 acc0 = (f32x4){0.f, 0.f, 0.f, 0.f};
  f32x4 acc1 = (f32x4){0.f, 0.f, 0.f, 0.f};
#pragma unroll 8
  for (int k32 = 0; k32 < 128; ++k32) {
    bf16x8 av  = *(const bf16x8*)(abase + (size_t)k32 * 512);
    bf16x8 bv0 = *(const bf16x8*)(brow0 + k32 * 32);
    bf16x8 bv1 = *(const bf16x8*)(brow1 + k32 * 32);
    acc0 = __builtin_amdgcn_mfma_f32_16x16x32_bf16(av, bv0, acc0, 0, 0, 0);
    acc1 = __builtin_amdgcn_mfma_f32_16x16x32_bf16(av, bv1, acc1, 0, 0, 0);
  }
  // C/D: row15 = (lane>>4)*4+r, col = lane&15 (acc0) / 16+(lane&15) (acc1).
  bf16* base = Aw + ((size_t)rb * NKB + 128) * 512;
  int c0 = lane & 15, c1 = 16 + (lane & 15);
#pragma unroll
  for (int r = 0; r < 4; ++r) {
    int row15 = ((lane >> 4) << 2) + r;
    base[(c0 >> 3) * 128 + row15 * 8 + (c0 & 7)] = __float2bfloat16(acc0[r]);
    base[(c1 >> 3) * 128 + row15 * 8 + (c1 & 7)] = __float2bfloat16(acc1[r]);
  }
}

// ---------------------------------------------------------------------------
// B-unpack: split-layout nibbles. lo nibbles -> rows 0..2047, hi -> 2048..4095.
__global__ __launch_bounds__(256) void prep_b(const int* __restrict__ packed,
                                              bf16* __restrict__ B) {
  size_t i = (size_t)blockIdx.x * 256 + threadIdx.x;   // [0, 2097152)
  int4 p = ((const int4*)packed)[i];
  size_t e = i * 4;
  int o = (int)(e >> 12);
  int c = (int)(e & 4095);
  int vals[4] = {p.x, p.y, p.z, p.w};
  unsigned short lo[4], hi[4];
#pragma unroll
  for (int j = 0; j < 4; ++j) {
    lo[j] = bf16_bits((float)((vals[j] & 15) - 8));
    hi[j] = bf16_bits((float)(((vals[j] >> 4) & 15) - 8));
  }
  *(ushort4*)(B + (size_t)o * KPAD + c) = make_ushort4(lo[0], lo[1], lo[2], lo[3]);
  *(ushort4*)(B + (size_t)(o + 2048) * KPAD + c) = make_ushort4(hi[0], hi[1], hi[2], hi[3]);
}

// ---------------------------------------------------------------------------
// Protected rows — MUST run after prep_b and prep_misc. Rows carry pc/s.
__global__ __launch_bounds__(256) void prep_prot(const float* __restrict__ pc,
                                                 const float* __restrict__ scales,
                                                 const int* __restrict__ pidx,
                                                 bf16* __restrict__ B) {
  int bi = blockIdx.x;            // [0, 32)
  int row = pidx[bi];
  bf16* Br = B + (size_t)row * KPAD;
  for (int c = threadIdx.x; c < KPAD; c += 256) {
    float val = (c < IN_F) ? pc[(size_t)bi * IN_F + c] / scales[c >> 7] : 0.f;
    Br[c] = __float2bfloat16(val);
  }
}

// ---------------------------------------------------------------------------
// Main GEMM, 256x256 tile, BK=64, 8 waves (4 row-bands x 2 col-bands).
// A: frag-major global -> VGPR, 1 coalesced 1KB txn per fragment.
// B: 4-deep LDS pipeline via global_load_lds, XOR-swizzled reads.
// ONE barrier per K-tile (end), counted vmcnt(4) — never drains to 0.
__global__ __launch_bounds__(512, 2) void gemm_bt(const bf16* __restrict__ A,
                                                  const bf16* __restrict__ B,
                                                  float* __restrict__ out) {
  __shared__ __align__(16) bf16 Bs[4 * 256 * 64];   // 128 KiB

  int bid = blockIdx.x;
  // XCD swizzle: 256 blocks, 8 XCDs, 32 contiguous per XCD.
  int swz = (bid & 7) * 32 + (bid >> 3);
  int brow = (swz >> 4) << 8;   // batch-row tile base
  int bcol = (swz & 15) << 8;   // out-col tile base

  int tid = threadIdx.x;
  int lane = tid & 63;
  int wave = tid >> 6;
  int wr = wave >> 1;           // 0..3 : 64-row band
  int wc = wave & 1;            // 0..1 : 128-col band

  f32x4 acc[4][8];
#pragma unroll
  for (int m = 0; m < 4; ++m)
#pragma unroll
    for (int n = 0; n < 8; ++n)
      acc[m][n] = (f32x4){0.f, 0.f, 0.f, 0.f};

  // A fragment base pointers (frag-major). Frag (m, kb): abase[m] + kb*1024.
  const char* abase[4];
  int rbw = (brow >> 4) + wr * 4;
#pragma unroll
  for (int m = 0; m < 4; ++m)
    abase[m] = (const char*)A + ((size_t)(rbw + m) * NKB) * 1024 + lane * 16;

  // B LDS frag byte offsets within one 32KB buffer (kk=0; kk=1 is ^64).
  int boff[8];
#pragma unroll
  for (int n = 0; n < 8; ++n) {
    int rbr = wc * 128 + n * 16 + (lane & 15);
    int s0 = (lane >> 4) ^ (rbr & 7);
    boff[n] = rbr * 128 + (s0 << 4);
  }

  // B staging: 4 rounds/tile; round q: idx = q*512+tid -> row=idx>>3, slot=idx&7.
  // LDS dest linear, global source slot pre-swizzled (slot ^ (row&7)).
  const bf16* gB[4]; int lB[4];
#pragma unroll
  for (int q = 0; q < 4; ++q) {
    int idx = q * 512 + tid;
    int row = idx >> 3, slot = idx & 7;
    gB[q] = B + (size_t)(bcol + row) * KPAD + ((slot ^ (row & 7)) << 3);
    lB[q] = idx << 4;          // byte offset within a buffer
  }
  char* bs0 = (char*)Bs;

  // ---- prologue: A(0) -> a0; stage B(0),B(1),B(2); keep newest 8 in flight.
  bf16x8 a0[4][2], a1[4][2];
#pragma unroll
  for (int m = 0; m < 4; ++m)
#pragma unroll
    for (int kk = 0; kk < 2; ++kk)
      a0[m][kk] = *(const bf16x8*)(abase[m] + kk * 1024);
#pragma unroll
  for (int kt = 0; kt < 3; ++kt)
#pragma unroll
    for (int q = 0; q < 4; ++q)
      gload_lds16(gB[q] + kt * 64, bs0 + kt * 32768 + lB[q]);
  asm volatile("s_waitcnt vmcnt(8)" ::: "memory");
  SBAR();

  // ---- tile body: no intra-tile barriers; one vmcnt(4)+SBAR per tile.
  auto tile_body = [&](int t, bf16x8 (&Au)[4][2], bf16x8 (&Ap)[4][2], bool pref) {
    const char* rb_ = bs0 + (t & 3) * 32768;         // read buffer
    char* wb = bs0 + ((t + 3) & 3) * 32768;          // stage dest buffer
    int kt = (t + 3 < NT) ? (t + 3) : (NT - 1);      // clamped (uniform count)
#pragma unroll
    for (int p = 0; p < 4; ++p) {
      if (p == 0 && pref) {
#pragma unroll
        for (int m = 0; m < 4; ++m)
#pragma unroll
          for (int kk = 0; kk < 2; ++kk)
            Ap[m][kk] = *(const bf16x8*)(abase[m] + (size_t)(2 * (t + 1) + kk) * 1024);
      }
      bf16x8 bv0k0 = *(const bf16x8*)(rb_ + boff[2 * p]);
      bf16x8 bv0k1 = *(const bf16x8*)(rb_ + (boff[2 * p] ^ 64));
      bf16x8 bv1k0 = *(const bf16x8*)(rb_ + boff[2 * p + 1]);
      bf16x8 bv1k1 = *(const bf16x8*)(rb_ + (boff[2 * p + 1] ^ 64));
      gload_lds16(gB[p] + (size_t)kt * 64, wb + lB[p]);   // 1 round/phase
      __builtin_amdgcn_s_setprio(1);
#pragma unroll
      for (int m = 0; m < 4; ++m) {
        acc[m][2 * p]     = __builtin_amdgcn_mfma_f32_16x16x32_bf16(Au[m][0], bv0k0, acc[m][2 * p], 0, 0, 0);
        acc[m][2 * p]     = __builtin_amdgcn_mfma_f32_16x16x32_bf16(Au[m][1], bv0k1, acc[m][2 * p], 0, 0, 0);
        acc[m][2 * p + 1] = __builtin_amdgcn_mfma_f32_16x16x32_bf16(Au[m][0], bv1k0, acc[m][2 * p + 1], 0, 0, 0);
        acc[m][2 * p + 1] = __builtin_amdgcn_mfma_f32_16x16x32_bf16(Au[m][1], bv1k1, acc[m][2 * p + 1], 0, 0, 0);
      }
      __builtin_amdgcn_s_setprio(0);
    }
    asm volatile("s_waitcnt vmcnt(4)" ::: "memory");
    SBAR();
  };

  for (int t = 0; t < NT - 1; t += 2) {
    tile_body(t, a0, a1, true);
    tile_body(t + 1, a1, a0, true);
  }
  tile_body(NT - 1, a0, a1, false);   // tail (NT odd: uses a0)

  // ---- epilogue: C/D col=lane&15 (o), row=(lane>>4)*4+r (batch); fp16 round.
#pragma unroll
  for (int m = 0; m < 4; ++m)
#pragma unroll
    for (int n = 0; n < 8; ++n)
#pragma unroll
      for (int r = 0; r < 4; ++r) {
        int mm = brow + wr * 64 + m * 16 + ((lane >> 4) << 2) + r;
        int nn = bcol + wc * 128 + n * 16 + (lane & 15);
        out[(size_t)mm * OUT_F + nn] = __half2float(__float2half(acc[m][n][r]));
      }
  asm volatile("s_waitcnt vmcnt(0)" ::: "memory");  // drain tail DMAs
}

// ---------------------------------------------------------------------------
extern "C" void kernel_launch(void* const* d_in, const int* in_sizes, int n_in,
                              void* d_out, int out_size, void* d_ws, size_t ws_size,
                              hipStream_t stream) {
  const float* x      = (const float*)d_in[0];
  const int*   packed = (const int*)d_in[1];
  const float* scales = (const float*)d_in[2];
  const float* svd_u  = (const float*)d_in[3];
  const float* svd_v  = (const float*)d_in[4];
  const float* pc     = (const float*)d_in[5];
  const int*   pidx   = (const int*)d_in[6];
  float* out = (float*)d_out;

  bf16* A   = (bf16*)d_ws;                     // frag-major [256][130] KB = 34.1 MB
  bf16* B   = A + (size_t)BATCH * KPAD;        // [OUT_F][KPAD] = 34.1 MB
  bf16* vst = B + (size_t)OUT_F * KPAD;        // [RANK][IN_F]  = 0.25 MB

  // ORDER MATTERS: prep_prot must be LAST writer of B's protected rows;
  // prep_t_mfma reads A written by prep_xs.
  prep_xs    <<<512,   256, 0, stream>>>(x, scales, A);
  prep_misc  <<<1536,  256, 0, stream>>>(svd_v, scales, svd_u, vst, B);
  prep_t_mfma<<<256,   64,  0, stream>>>(A, vst, A);
  prep_b     <<<8192,  256, 0, stream>>>(packed, B);
  prep_prot  <<<32,    256, 0, stream>>>(pc, scales, pidx, B);
  gemm_bt    <<<256,   512, 0, stream>>>(A, B, out);
}

// Round 10
// 289.516 us; speedup vs baseline: 1.3130x; 1.1348x over previous
//
#include <hip/hip_runtime.h>
#include <hip/hip_bf16.h>
#include <hip/hip_fp16.h>

#define OUT_F 4096
#define IN_F  4096
#define BATCH 4096
#define RANK  32
#define KPAD  4160   // 4096 + 32 (svd ext) + 32 (zero pad) = 65 * 64 = 130 * 32
#define NKB   130    // k32-blocks per row-panel
#define NT    65     // K tiles of 64

typedef __hip_bfloat16 bf16;
using bf16x8 = __attribute__((ext_vector_type(8))) short;
using f32x4  = __attribute__((ext_vector_type(4))) float;

// Fragment-major A layout: frag(rb=row>>4, kb=k>>5) = 1024B at ((rb*NKB+kb)*1024);
// within it, lane = koct*16 + (row&15) holds bf16x8 of k = kb*32 + koct*8 ..+8.

__device__ __forceinline__ void gload_lds16(const void* g, void* l) {
  __builtin_amdgcn_global_load_lds(
      (const __attribute__((address_space(1))) unsigned int*)g,
      (__attribute__((address_space(3))) unsigned int*)l,
      16, 0, 0);
}

__device__ __forceinline__ unsigned short bf16_bits(float f) {
  bf16 h = __float2bfloat16(f);
  return *(unsigned short*)&h;
}

#define SBAR() asm volatile("s_barrier" ::: "memory")

// ---------------------------------------------------------------------------
// Small prep: [0,512) VsT[r][c] = V[c][r]/s[c/128]; [512,1536) B ext cols:
// U values (0 for protected rows), 0 pad.
__global__ __launch_bounds__(256) void prep_misc(const float* __restrict__ v,
                                                 const float* __restrict__ scales,
                                                 const float* __restrict__ u,
                                                 const int* __restrict__ pidx,
                                                 bf16* __restrict__ vst,
                                                 bf16* __restrict__ B) {
  int bid = blockIdx.x;
  if (bid < 512) {
    int gid = bid * 256 + threadIdx.x;       // [0, 131072)
    int c = gid >> 5, r = gid & 31;
    float val = v[(size_t)c * RANK + r] / scales[c >> 7];
    vst[(size_t)r * IN_F + c] = __float2bfloat16(val);
  } else {
    int i = (bid - 512) * 256 + threadIdx.x; // [0, 262144)
    int o = i >> 6, j = i & 63;
    float val = (j < RANK) ? u[o * RANK + j] : 0.f;
#pragma unroll
    for (int jj = 0; jj < 32; ++jj)
      if (pidx[jj] == o) val = 0.f;          // protected rows: no SVD term
    B[(size_t)o * KPAD + IN_F + j] = __float2bfloat16(val);
  }
}

// ---------------------------------------------------------------------------
// Fused A-prep: phase 1 writes xs = x*s frag-major (coalesced reads via LDS
// transpose, XOR-swizzled); phase 2 computes T = xs @ VsT^T (K split over the
// 8 waves, LDS reduce) into frag kb=128, zeroes pad frag kb=129.
__global__ __launch_bounds__(512) void prep_a(const float* __restrict__ x,
                                              const float* __restrict__ scales,
                                              const bf16* __restrict__ vst,
                                              bf16* __restrict__ A) {
  __shared__ __align__(16) char lds[16384];
  int rb = blockIdx.x;                 // row-block 0..255
  int tid = threadIdx.x, w = tid >> 6, l = tid & 63;

  // ---- phase 1: 8 chunks of k512; wave w stages rows w*2, w*2+1 ----
  for (int c = 0; c < 8; ++c) {
#pragma unroll
    for (int j = 0; j < 2; ++j) {
      int r = w * 2 + j;               // 0..15
      const float* xr = x + (size_t)(rb * 16 + r) * IN_F + c * 512 + l * 8;
      float sv = scales[(c * 512 + l * 8) >> 7];
      float4 v0 = *(const float4*)xr;
      float4 v1 = *(const float4*)(xr + 4);
      bf16x8 pk;
      pk[0] = (short)bf16_bits(v0.x * sv); pk[1] = (short)bf16_bits(v0.y * sv);
      pk[2] = (short)bf16_bits(v0.z * sv); pk[3] = (short)bf16_bits(v0.w * sv);
      pk[4] = (short)bf16_bits(v1.x * sv); pk[5] = (short)bf16_bits(v1.y * sv);
      pk[6] = (short)bf16_bits(v1.z * sv); pk[7] = (short)bf16_bits(v1.w * sv);
      int kb = l >> 2;                 // local frag 0..15 (koct = l&3)
      int byte = kb * 1024 + (((l & 3) << 4) + r) * 16;
      *(bf16x8*)(lds + (byte ^ ((kb & 7) << 4))) = pk;
    }
    __syncthreads();
#pragma unroll
    for (int j = 0; j < 2; ++j) {
      int f = w * 2 + j;
      int byte = f * 1024 + l * 16;
      bf16x8 pk = *(const bf16x8*)(lds + (byte ^ ((f & 7) << 4)));
      *(bf16x8*)(A + ((size_t)rb * NKB + c * 16 + f) * 512 + (size_t)l * 8) = pk;
    }
    __syncthreads();
  }

  // ---- phase 2: T for these 16 rows; wave w covers k32 [w*16, w*16+16) ----
  const bf16* abase = A + (size_t)rb * NKB * 512 + (size_t)l * 8;
  const bf16* brow0 = vst + (size_t)(l & 15) * IN_F + ((l >> 4) << 3);
  const bf16* brow1 = vst + (size_t)(16 + (l & 15)) * IN_F + ((l >> 4) << 3);
  f32x4 acc0 = (f32x4){0.f, 0.f, 0.f, 0.f};
  f32x4 acc1 = (f32x4){0.f, 0.f, 0.f, 0.f};
#pragma unroll 8
  for (int k32 = w * 16; k32 < w * 16 + 16; ++k32) {
    bf16x8 av  = *(const bf16x8*)(abase + (size_t)k32 * 512);
    bf16x8 bv0 = *(const bf16x8*)(brow0 + k32 * 32);
    bf16x8 bv1 = *(const bf16x8*)(brow1 + k32 * 32);
    acc0 = __builtin_amdgcn_mfma_f32_16x16x32_bf16(av, bv0, acc0, 0, 0, 0);
    acc1 = __builtin_amdgcn_mfma_f32_16x16x32_bf16(av, bv1, acc1, 0, 0, 0);
  }
  *(f32x4*)(lds + w * 2048 + l * 32)      = acc0;
  *(f32x4*)(lds + w * 2048 + l * 32 + 16) = acc1;
  __syncthreads();
  if (w == 1) {  // zero pad frag kb=129
    bf16x8 z = (bf16x8){0, 0, 0, 0, 0, 0, 0, 0};
    *(bf16x8*)(A + ((size_t)rb * NKB + 129) * 512 + (size_t)l * 8) = z;
  }
  if (w == 0) {
#pragma unroll
    for (int ww = 1; ww < 8; ++ww) {
      acc0 += *(const f32x4*)(lds + ww * 2048 + l * 32);
      acc1 += *(const f32x4*)(lds + ww * 2048 + l * 32 + 16);
    }
    // C/D: row15 = (l>>4)*4+r, cols l&15 and 16+(l&15); frag-major element
    // (row15, col) at koct*128 + row15*8 + (col&7).
    bf16* base = A + ((size_t)rb * NKB + 128) * 512;
    int c0 = l & 15, c1 = 16 + (l & 15);
#pragma unroll
    for (int r = 0; r < 4; ++r) {
      int row15 = ((l >> 4) << 2) + r;
      base[(c0 >> 3) * 128 + row15 * 8 + (c0 & 7)] = __float2bfloat16(acc0[r]);
      base[(c1 >> 3) * 128 + row15 * 8 + (c1 & 7)] = __float2bfloat16(acc1[r]);
    }
  }
}

// ---------------------------------------------------------------------------
// B-unpack with fused protected-row overwrite (no ordering hazard): row o of
// the dequant weights, but pc/s if o is protected. lo nibbles -> rows 0..2047,
// hi nibbles -> rows 2048..4095. Each block covers one quarter-row per half
// (uniform branch).
__global__ __launch_bounds__(256) void prep_b(const int* __restrict__ packed,
                                              const float* __restrict__ pc,
                                              const float* __restrict__ scales,
                                              const int* __restrict__ pidx,
                                              bf16* __restrict__ B) {
  size_t i = (size_t)blockIdx.x * 256 + threadIdx.x;   // [0, 2097152)
  int4 p = ((const int4*)packed)[i];
  size_t e = i * 4;
  int o = (int)(e >> 12);
  int c = (int)(e & 4095);
  int pi_lo = -1, pi_hi = -1;
#pragma unroll
  for (int j = 0; j < 32; ++j) {
    int pr = pidx[j];
    if (pr == o) pi_lo = j;
    if (pr == o + 2048) pi_hi = j;
  }
  int vals[4] = {p.x, p.y, p.z, p.w};
  unsigned short lo[4], hi[4];
#pragma unroll
  for (int j = 0; j < 4; ++j) {
    lo[j] = bf16_bits((float)((vals[j] & 15) - 8));
    hi[j] = bf16_bits((float)(((vals[j] >> 4) & 15) - 8));
  }
  if (pi_lo >= 0) {
    float sv = scales[c >> 7];
#pragma unroll
    for (int j = 0; j < 4; ++j)
      lo[j] = bf16_bits(pc[(size_t)pi_lo * IN_F + c + j] / sv);
  }
  if (pi_hi >= 0) {
    float sv = scales[c >> 7];
#pragma unroll
    for (int j = 0; j < 4; ++j)
      hi[j] = bf16_bits(pc[(size_t)pi_hi * IN_F + c + j] / sv);
  }
  *(ushort4*)(B + (size_t)o * KPAD + c) = make_ushort4(lo[0], lo[1], lo[2], lo[3]);
  *(ushort4*)(B + (size_t)(o + 2048) * KPAD + c) = make_ushort4(hi[0], hi[1], hi[2], hi[3]);
}

// ---------------------------------------------------------------------------
// Main GEMM, 256x256 tile, BK=64, 8 waves (4 row-bands x 2 col-bands).
// A: frag-major global -> VGPR, 1 coalesced 1KB txn per fragment.
// B: 4-deep LDS pipeline via global_load_lds, XOR-swizzled reads.
// ONE barrier per K-tile (end), counted vmcnt(4) — never drains to 0.
__global__ __launch_bounds__(512, 2) void gemm_bt(const bf16* __restrict__ A,
                                                  const bf16* __restrict__ B,
                                                  float* __restrict__ out) {
  __shared__ __align__(16) bf16 Bs[4 * 256 * 64];   // 128 KiB

  int bid = blockIdx.x;
  // XCD swizzle: 256 blocks, 8 XCDs, 32 contiguous per XCD.
  int swz = (bid & 7) * 32 + (bid >> 3);
  int brow = (swz >> 4) << 8;   // batch-row tile base
  int bcol = (swz & 15) << 8;   // out-col tile base

  int tid = threadIdx.x;
  int lane = tid & 63;
  int wave = tid >> 6;
  int wr = wave >> 1;           // 0..3 : 64-row band
  int wc = wave & 1;            // 0..1 : 128-col band

  f32x4 acc[4][8];
#pragma unroll
  for (int m = 0; m < 4; ++m)
#pragma unroll
    for (int n = 0; n < 8; ++n)
      acc[m][n] = (f32x4){0.f, 0.f, 0.f, 0.f};

  // A fragment base pointers (frag-major). Frag (m, kb): abase[m] + kb*1024.
  const char* abase[4];
  int rbw = (brow >> 4) + wr * 4;
#pragma unroll
  for (int m = 0; m < 4; ++m)
    abase[m] = (const char*)A + ((size_t)(rbw + m) * NKB) * 1024 + lane * 16;

  // B LDS frag byte offsets within one 32KB buffer (kk=0; kk=1 is ^64).
  int boff[8];
#pragma unroll
  for (int n = 0; n < 8; ++n) {
    int rbr = wc * 128 + n * 16 + (lane & 15);
    int s0 = (lane >> 4) ^ (rbr & 7);
    boff[n] = rbr * 128 + (s0 << 4);
  }

  // B staging: 4 rounds/tile; round q: idx = q*512+tid -> row=idx>>3, slot=idx&7.
  // LDS dest linear, global source slot pre-swizzled (slot ^ (row&7)).
  const bf16* gB[4]; int lB[4];
#pragma unroll
  for (int q = 0; q < 4; ++q) {
    int idx = q * 512 + tid;
    int row = idx >> 3, slot = idx & 7;
    gB[q] = B + (size_t)(bcol + row) * KPAD + ((slot ^ (row & 7)) << 3);
    lB[q] = idx << 4;          // byte offset within a buffer
  }
  char* bs0 = (char*)Bs;

  // ---- prologue: A(0) -> a0; stage B(0),B(1),B(2); keep newest 8 in flight.
  bf16x8 a0[4][2], a1[4][2];
#pragma unroll
  for (int m = 0; m < 4; ++m)
#pragma unroll
    for (int kk = 0; kk < 2; ++kk)
      a0[m][kk] = *(const bf16x8*)(abase[m] + kk * 1024);
#pragma unroll
  for (int kt = 0; kt < 3; ++kt)
#pragma unroll
    for (int q = 0; q < 4; ++q)
      gload_lds16(gB[q] + kt * 64, bs0 + kt * 32768 + lB[q]);
  asm volatile("s_waitcnt vmcnt(8)" ::: "memory");
  SBAR();

  // ---- tile body: no intra-tile barriers; one vmcnt(4)+SBAR per tile.
  auto tile_body = [&](int t, bf16x8 (&Au)[4][2], bf16x8 (&Ap)[4][2], bool pref) {
    const char* rb_ = bs0 + (t & 3) * 32768;         // read buffer
    char* wb = bs0 + ((t + 3) & 3) * 32768;          // stage dest buffer
    int kt = (t + 3 < NT) ? (t + 3) : (NT - 1);      // clamped (uniform count)
#pragma unroll
    for (int p = 0; p < 4; ++p) {
      if (p == 0 && pref) {
#pragma unroll
        for (int m = 0; m < 4; ++m)
#pragma unroll
          for (int kk = 0; kk < 2; ++kk)
            Ap[m][kk] = *(const bf16x8*)(abase[m] + (size_t)(2 * (t + 1) + kk) * 1024);
      }
      bf16x8 bv0k0 = *(const bf16x8*)(rb_ + boff[2 * p]);
      bf16x8 bv0k1 = *(const bf16x8*)(rb_ + (boff[2 * p] ^ 64));
      bf16x8 bv1k0 = *(const bf16x8*)(rb_ + boff[2 * p + 1]);
      bf16x8 bv1k1 = *(const bf16x8*)(rb_ + (boff[2 * p + 1] ^ 64));
      gload_lds16(gB[p] + (size_t)kt * 64, wb + lB[p]);   // 1 round/phase
      __builtin_amdgcn_s_setprio(1);
#pragma unroll
      for (int m = 0; m < 4; ++m) {
        acc[m][2 * p]     = __builtin_amdgcn_mfma_f32_16x16x32_bf16(Au[m][0], bv0k0, acc[m][2 * p], 0, 0, 0);
        acc[m][2 * p]     = __builtin_amdgcn_mfma_f32_16x16x32_bf16(Au[m][1], bv0k1, acc[m][2 * p], 0, 0, 0);
        acc[m][2 * p + 1] = __builtin_amdgcn_mfma_f32_16x16x32_bf16(Au[m][0], bv1k0, acc[m][2 * p + 1], 0, 0, 0);
        acc[m][2 * p + 1] = __builtin_amdgcn_mfma_f32_16x16x32_bf16(Au[m][1], bv1k1, acc[m][2 * p + 1], 0, 0, 0);
      }
      __builtin_amdgcn_s_setprio(0);
    }
    asm volatile("s_waitcnt vmcnt(4)" ::: "memory");
    SBAR();
  };

  for (int t = 0; t < NT - 1; t += 2) {
    tile_body(t, a0, a1, true);
    tile_body(t + 1, a1, a0, true);
  }
  tile_body(NT - 1, a0, a1, false);   // tail (NT odd: uses a0)

  // ---- epilogue: C/D col=lane&15 (o), row=(lane>>4)*4+r (batch); fp16 round.
#pragma unroll
  for (int m = 0; m < 4; ++m)
#pragma unroll
    for (int n = 0; n < 8; ++n)
#pragma unroll
      for (int r = 0; r < 4; ++r) {
        int mm = brow + wr * 64 + m * 16 + ((lane >> 4) << 2) + r;
        int nn = bcol + wc * 128 + n * 16 + (lane & 15);
        out[(size_t)mm * OUT_F + nn] = __half2float(__float2half(acc[m][n][r]));
      }
  asm volatile("s_waitcnt vmcnt(0)" ::: "memory");  // drain tail DMAs
}

// ---------------------------------------------------------------------------
extern "C" void kernel_launch(void* const* d_in, const int* in_sizes, int n_in,
                              void* d_out, int out_size, void* d_ws, size_t ws_size,
                              hipStream_t stream) {
  const float* x      = (const float*)d_in[0];
  const int*   packed = (const int*)d_in[1];
  const float* scales = (const float*)d_in[2];
  const float* svd_u  = (const float*)d_in[3];
  const float* svd_v  = (const float*)d_in[4];
  const float* pc     = (const float*)d_in[5];
  const int*   pidx   = (const int*)d_in[6];
  float* out = (float*)d_out;

  bf16* A   = (bf16*)d_ws;                     // frag-major, 34.1 MB
  bf16* B   = A + (size_t)BATCH * KPAD;        // [OUT_F][KPAD] = 34.1 MB
  bf16* vst = B + (size_t)OUT_F * KPAD;        // [RANK][IN_F]  = 0.25 MB

  // prep_a needs vst (from prep_misc). Protected rows are fused into
  // prep_b/prep_misc — no ordering hazard remains.
  prep_misc<<<1536, 256, 0, stream>>>(svd_v, scales, svd_u, pidx, vst, B);
  prep_a   <<<256,  512, 0, stream>>>(x, scales, vst, A);
  prep_b   <<<8192, 256, 0, stream>>>(packed, pc, scales, pidx, B);
  gemm_bt  <<<256,  512, 0, stream>>>(A, B, out);
}